// Round 1
// baseline (537.127 us; speedup 1.0000x reference)
//
#include <hip/hip_runtime.h>
#include <hip/hip_bf16.h>

typedef short v8s __attribute__((ext_vector_type(8)));
typedef float v4f __attribute__((ext_vector_type(4)));

#define BS 4
#define SEQ 2048
#define DMODEL 768
#define HEADS 12
#define GROUPS 2
#define DK 64
#define MROWS (BS * SEQ)  // 8192

static __device__ __forceinline__ short f2bs(float f) {
    __hip_bfloat16 h = __float2bfloat16(f);
    return *reinterpret_cast<short*>(&h);
}

struct alignas(8) s4pack { short a, b, c, d; };

// ---------------------------------------------------------------------------
// Projection GEMM: C[M=8192, N] = A[8192,768] @ W[768,N] + bias, bf16 out.
// mode 0: Q -> [b, h, s, d]   (N=768)
// mode 1: K -> [b, g, s, d]   (N=128)
// mode 2: V -> [b, g, d, s]   (transposed, N=128)
// Tiles: BM=128, BN=128, BK=32. 256 threads = 4 waves in 2x2, each wave 64x64.
// ---------------------------------------------------------------------------
__global__ __launch_bounds__(256) void proj_kernel(
    const float* __restrict__ A, const float* __restrict__ W,
    const float* __restrict__ bias, short* __restrict__ out,
    int N, int mode)
{
    const int LS = 40;  // padded LDS stride (2-way bank conflicts only)
    __shared__ short lA[128 * 40];
    __shared__ short lB[128 * 40];

    const int tid  = threadIdx.x;
    const int lane = tid & 63;
    const int wid  = tid >> 6;
    const int l16  = lane & 15;
    const int quad = lane >> 4;
    const int wm   = wid & 1;
    const int wn   = wid >> 1;
    const int bm   = blockIdx.x;
    const int bn   = blockIdx.y;

    v4f acc[4][4];
#pragma unroll
    for (int i = 0; i < 4; ++i)
#pragma unroll
        for (int j = 0; j < 4; ++j) acc[i][j] = (v4f){0.f, 0.f, 0.f, 0.f};

    for (int kt = 0; kt < 24; ++kt) {
        const int k0 = kt * 32;
        // ---- stage A tile [128 rows][32 k] fp32 -> bf16
#pragma unroll
        for (int r = 0; r < 4; ++r) {
            int f4  = tid + 256 * r;
            int row = f4 >> 3;
            int c4  = (f4 & 7) << 2;
            const float4 a = *reinterpret_cast<const float4*>(
                A + (size_t)(bm * 128 + row) * DMODEL + k0 + c4);
            s4pack p{f2bs(a.x), f2bs(a.y), f2bs(a.z), f2bs(a.w)};
            *reinterpret_cast<s4pack*>(&lA[row * LS + c4]) = p;
        }
        // ---- stage B tile [32 k][128 n] -> LDS transposed [n][k]
#pragma unroll
        for (int r = 0; r < 4; ++r) {
            int f4  = tid + 256 * r;
            int kr  = f4 >> 5;
            int nc4 = (f4 & 31) << 2;
            const float4 w = *reinterpret_cast<const float4*>(
                W + (size_t)(k0 + kr) * N + bn * 128 + nc4);
            lB[(nc4 + 0) * LS + kr] = f2bs(w.x);
            lB[(nc4 + 1) * LS + kr] = f2bs(w.y);
            lB[(nc4 + 2) * LS + kr] = f2bs(w.z);
            lB[(nc4 + 3) * LS + kr] = f2bs(w.w);
        }
        __syncthreads();

        v8s af[4], bf[4];
#pragma unroll
        for (int i = 0; i < 4; ++i)
            af[i] = *reinterpret_cast<const v8s*>(&lA[(wm * 64 + i * 16 + l16) * LS + quad * 8]);
#pragma unroll
        for (int j = 0; j < 4; ++j)
            bf[j] = *reinterpret_cast<const v8s*>(&lB[(wn * 64 + j * 16 + l16) * LS + quad * 8]);
#pragma unroll
        for (int i = 0; i < 4; ++i)
#pragma unroll
            for (int j = 0; j < 4; ++j)
                acc[i][j] = __builtin_amdgcn_mfma_f32_16x16x32_bf16(af[i], bf[j], acc[i][j], 0, 0, 0);
        __syncthreads();
    }

    // ---- epilogue
#pragma unroll
    for (int i = 0; i < 4; ++i) {
#pragma unroll
        for (int j = 0; j < 4; ++j) {
            const int C = bn * 128 + wn * 64 + j * 16 + l16;
            const float bv = bias[C];
#pragma unroll
            for (int reg = 0; reg < 4; ++reg) {
                const int R = bm * 128 + wm * 64 + i * 16 + quad * 4 + reg;
                const float val = acc[i][j][reg] + bv;
                const int b = R >> 11;       // /2048
                const int s = R & 2047;
                const int sub = C >> 6;      // head or group
                const int d = C & 63;
                size_t idx;
                if (mode == 0)      idx = ((size_t)(b * HEADS + sub) * SEQ + s) * DK + d;
                else if (mode == 1) idx = ((size_t)(b * GROUPS + sub) * SEQ + s) * DK + d;
                else                idx = ((size_t)(b * GROUPS + sub) * DK + d) * SEQ + s;
                out[idx] = f2bs(val);
            }
        }
    }
}

// ---------------------------------------------------------------------------
// Flash attention (non-causal, UNSCALED scores — faithful to reference).
// grid (32 qtiles, 12 heads, 4 batch), 256 threads = 4 waves.
// Each wave: 16 Q rows. Loop over 32 K-tiles of 64 rows.
// ---------------------------------------------------------------------------
__global__ __launch_bounds__(256) void attn_kernel(
    const short* __restrict__ Qp, const short* __restrict__ Kp,
    const short* __restrict__ Vt, short* __restrict__ Oat)
{
    const int LS = 72;  // padded stride: 2-way conflicts only
    __shared__ short lK[64 * 72];       // [k_row][d]
    __shared__ short lV[64 * 72];       // [d][k_row]   (from transposed V)
    __shared__ short lP[4][16 * 72];    // per-wave P tile [q_row][k_row]

    const int qt = blockIdx.x, h = blockIdx.y, b = blockIdx.z;
    const int g = h & 1;
    const int tid  = threadIdx.x;
    const int lane = tid & 63;
    const int wid  = tid >> 6;
    const int l16  = lane & 15;
    const int quad = lane >> 4;

    // Q fragments (A-operand layout), resident for whole kernel
    const size_t qbase = ((size_t)(b * HEADS + h) * SEQ + qt * 64 + wid * 16 + l16) * DK;
    const v8s qf0 = *reinterpret_cast<const v8s*>(Qp + qbase + quad * 8);
    const v8s qf1 = *reinterpret_cast<const v8s*>(Qp + qbase + quad * 8 + 32);

    const size_t kbase = (size_t)(b * GROUPS + g) * SEQ * DK;
    const size_t vbase = (size_t)(b * GROUPS + g) * DK * SEQ;

    v4f oacc[4];
#pragma unroll
    for (int n = 0; n < 4; ++n) oacc[n] = (v4f){0.f, 0.f, 0.f, 0.f};
    float m[4] = {-1e30f, -1e30f, -1e30f, -1e30f};
    float lsum[4] = {0.f, 0.f, 0.f, 0.f};

    for (int kt = 0; kt < 32; ++kt) {
        // ---- stage K tile [64][64] and V^T tile [64][64]
#pragma unroll
        for (int r = 0; r < 2; ++r) {
            int b8  = tid + 256 * r;
            int row = b8 >> 3;
            int c8  = (b8 & 7) << 3;
            *reinterpret_cast<v8s*>(&lK[row * LS + c8]) =
                *reinterpret_cast<const v8s*>(Kp + kbase + (size_t)(kt * 64 + row) * DK + c8);
            *reinterpret_cast<v8s*>(&lV[row * LS + c8]) =
                *reinterpret_cast<const v8s*>(Vt + vbase + (size_t)row * SEQ + kt * 64 + c8);
        }
        __syncthreads();

        // ---- S = Q K^T  (16 q-rows x 64 k-cols per wave)
        v4f sacc[4];
#pragma unroll
        for (int j = 0; j < 4; ++j) {
            const v8s kf0 = *reinterpret_cast<const v8s*>(&lK[(j * 16 + l16) * LS + quad * 8]);
            const v8s kf1 = *reinterpret_cast<const v8s*>(&lK[(j * 16 + l16) * LS + quad * 8 + 32]);
            v4f z = (v4f){0.f, 0.f, 0.f, 0.f};
            z = __builtin_amdgcn_mfma_f32_16x16x32_bf16(qf0, kf0, z, 0, 0, 0);
            sacc[j] = __builtin_amdgcn_mfma_f32_16x16x32_bf16(qf1, kf1, z, 0, 0, 0);
        }

        // ---- online softmax
        float rmax[4], rsum[4];
#pragma unroll
        for (int reg = 0; reg < 4; ++reg)
            rmax[reg] = fmaxf(fmaxf(sacc[0][reg], sacc[1][reg]), fmaxf(sacc[2][reg], sacc[3][reg]));
#pragma unroll
        for (int d = 1; d < 16; d <<= 1)
#pragma unroll
            for (int reg = 0; reg < 4; ++reg)
                rmax[reg] = fmaxf(rmax[reg], __shfl_xor(rmax[reg], d, 64));

        float alpha[4];
#pragma unroll
        for (int reg = 0; reg < 4; ++reg) {
            const float mn = fmaxf(m[reg], rmax[reg]);
            alpha[reg] = __expf(m[reg] - mn);
            m[reg] = mn;
        }
        float p[4][4];
#pragma unroll
        for (int reg = 0; reg < 4; ++reg) rsum[reg] = 0.f;
#pragma unroll
        for (int j = 0; j < 4; ++j)
#pragma unroll
            for (int reg = 0; reg < 4; ++reg) {
                p[j][reg] = __expf(sacc[j][reg] - m[reg]);
                rsum[reg] += p[j][reg];
            }
#pragma unroll
        for (int d = 1; d < 16; d <<= 1)
#pragma unroll
            for (int reg = 0; reg < 4; ++reg)
                rsum[reg] += __shfl_xor(rsum[reg], d, 64);
#pragma unroll
        for (int reg = 0; reg < 4; ++reg)
            lsum[reg] = lsum[reg] * alpha[reg] + rsum[reg];
#pragma unroll
        for (int n = 0; n < 4; ++n)
#pragma unroll
            for (int reg = 0; reg < 4; ++reg) oacc[n][reg] *= alpha[reg];

        // ---- P: C-layout -> LDS -> A-layout
#pragma unroll
        for (int j = 0; j < 4; ++j)
#pragma unroll
            for (int reg = 0; reg < 4; ++reg)
                lP[wid][(quad * 4 + reg) * LS + j * 16 + l16] = f2bs(p[j][reg]);
        __syncthreads();

        // ---- O += P V
#pragma unroll
        for (int kk = 0; kk < 2; ++kk) {
            const v8s pf = *reinterpret_cast<const v8s*>(&lP[wid][l16 * LS + quad * 8 + kk * 32]);
#pragma unroll
            for (int n = 0; n < 4; ++n) {
                const v8s vf = *reinterpret_cast<const v8s*>(&lV[(n * 16 + l16) * LS + quad * 8 + kk * 32]);
                oacc[n] = __builtin_amdgcn_mfma_f32_16x16x32_bf16(pf, vf, oacc[n], 0, 0, 0);
            }
        }
        __syncthreads();
    }

    // ---- epilogue: O /= l, write [b, s, h*64+d] bf16 for the output GEMM
#pragma unroll
    for (int n = 0; n < 4; ++n)
#pragma unroll
        for (int reg = 0; reg < 4; ++reg) {
            const float val = oacc[n][reg] / lsum[reg];
            const int qrow = qt * 64 + wid * 16 + quad * 4 + reg;
            Oat[(size_t)(b * SEQ + qrow) * DMODEL + h * 64 + n * 16 + l16] = f2bs(val);
        }
}

// ---------------------------------------------------------------------------
// Output GEMM: out[8192,768] = Oat(bf16)[8192,768] @ Wo[768,768] + bo, fp32 out
// ---------------------------------------------------------------------------
__global__ __launch_bounds__(256) void out_gemm(
    const short* __restrict__ A, const float* __restrict__ W,
    const float* __restrict__ bias, float* __restrict__ out)
{
    const int LS = 40;
    __shared__ short lA[128 * 40];
    __shared__ short lB[128 * 40];

    const int tid  = threadIdx.x;
    const int lane = tid & 63;
    const int wid  = tid >> 6;
    const int l16  = lane & 15;
    const int quad = lane >> 4;
    const int wm   = wid & 1;
    const int wn   = wid >> 1;
    const int bm   = blockIdx.x;
    const int bn   = blockIdx.y;

    v4f acc[4][4];
#pragma unroll
    for (int i = 0; i < 4; ++i)
#pragma unroll
        for (int j = 0; j < 4; ++j) acc[i][j] = (v4f){0.f, 0.f, 0.f, 0.f};

    for (int kt = 0; kt < 24; ++kt) {
        const int k0 = kt * 32;
        // stage A (already bf16): 16B vector loads
#pragma unroll
        for (int r = 0; r < 2; ++r) {
            int b8  = tid + 256 * r;
            int row = b8 >> 2;
            int c8  = (b8 & 3) << 3;
            *reinterpret_cast<v8s*>(&lA[row * LS + c8]) =
                *reinterpret_cast<const v8s*>(A + (size_t)(bm * 128 + row) * DMODEL + k0 + c8);
        }
        // stage B transposed + converted
#pragma unroll
        for (int r = 0; r < 4; ++r) {
            int f4  = tid + 256 * r;
            int kr  = f4 >> 5;
            int nc4 = (f4 & 31) << 2;
            const float4 w = *reinterpret_cast<const float4*>(
                W + (size_t)(k0 + kr) * DMODEL + bn * 128 + nc4);
            lB[(nc4 + 0) * LS + kr] = f2bs(w.x);
            lB[(nc4 + 1) * LS + kr] = f2bs(w.y);
            lB[(nc4 + 2) * LS + kr] = f2bs(w.z);
            lB[(nc4 + 3) * LS + kr] = f2bs(w.w);
        }
        __syncthreads();

        v8s af[4], bf[4];
#pragma unroll
        for (int i = 0; i < 4; ++i)
            af[i] = *reinterpret_cast<const v8s*>(&lA[(wm * 64 + i * 16 + l16) * LS + quad * 8]);
#pragma unroll
        for (int j = 0; j < 4; ++j)
            bf[j] = *reinterpret_cast<const v8s*>(&lB[(wn * 64 + j * 16 + l16) * LS + quad * 8]);
#pragma unroll
        for (int i = 0; i < 4; ++i)
#pragma unroll
            for (int j = 0; j < 4; ++j)
                acc[i][j] = __builtin_amdgcn_mfma_f32_16x16x32_bf16(af[i], bf[j], acc[i][j], 0, 0, 0);
        __syncthreads();
    }

#pragma unroll
    for (int i = 0; i < 4; ++i)
#pragma unroll
        for (int j = 0; j < 4; ++j) {
            const int C = bn * 128 + wn * 64 + j * 16 + l16;
            const float bv = bias[C];
#pragma unroll
            for (int reg = 0; reg < 4; ++reg) {
                const int R = bm * 128 + wm * 64 + i * 16 + quad * 4 + reg;
                out[(size_t)R * DMODEL + C] = acc[i][j][reg] + bv;
            }
        }
}

extern "C" void kernel_launch(void* const* d_in, const int* in_sizes, int n_in,
                              void* d_out, int out_size, void* d_ws, size_t ws_size,
                              hipStream_t stream) {
    const float* q  = (const float*)d_in[0];
    const float* k  = (const float*)d_in[1];
    const float* v  = (const float*)d_in[2];
    const float* Wq = (const float*)d_in[3];
    const float* bq = (const float*)d_in[4];
    const float* Wk = (const float*)d_in[5];
    const float* bk = (const float*)d_in[6];
    const float* Wv = (const float*)d_in[7];
    const float* bv = (const float*)d_in[8];
    const float* Wo = (const float*)d_in[9];
    const float* bo = (const float*)d_in[10];

    short* Qp  = (short*)d_ws;                              // [b,h,s,d]  6291456
    short* Kp  = Qp + (size_t)BS * HEADS * SEQ * DK;        // [b,g,s,d]  2097152
    short* Vt  = Kp + (size_t)BS * GROUPS * SEQ * DK;       // [b,g,d,s]  2097152
    short* Oat = Vt + (size_t)BS * GROUPS * SEQ * DK;       // [b,s,h*d]  6291456

    proj_kernel<<<dim3(64, 6), 256, 0, stream>>>(q, Wq, bq, Qp, DMODEL, 0);
    proj_kernel<<<dim3(64, 1), 256, 0, stream>>>(k, Wk, bk, Kp, GROUPS * DK, 1);
    proj_kernel<<<dim3(64, 1), 256, 0, stream>>>(v, Wv, bv, Vt, GROUPS * DK, 2);
    attn_kernel<<<dim3(32, HEADS, BS), 256, 0, stream>>>(Qp, Kp, Vt, Oat);
    out_gemm<<<dim3(64, 6), 256, 0, stream>>>(Oat, Wo, bo, (float*)d_out);
}

// Round 2
// 349.726 us; speedup vs baseline: 1.5359x; 1.5359x over previous
//
#include <hip/hip_runtime.h>
#include <hip/hip_bf16.h>

typedef short v8s __attribute__((ext_vector_type(8)));
typedef float v4f __attribute__((ext_vector_type(4)));

#define BS 4
#define SEQ 2048
#define DMODEL 768
#define HEADS 12
#define GROUPS 2
#define DK 64
#define LOG2E 1.4426950408889634f

static __device__ __forceinline__ short f2bs(float f) {
    __hip_bfloat16 h = __float2bfloat16(f);
    return *reinterpret_cast<short*>(&h);
}

static __device__ __forceinline__ float fast_exp2(float x) {
#if __has_builtin(__builtin_amdgcn_exp2f)
    return __builtin_amdgcn_exp2f(x);
#else
    return __expf(x * 0.6931471805599453f);
#endif
}

struct alignas(8) s4pack { short a, b, c, d; };

// ---------------------------------------------------------------------------
// Weight transpose + fp32->bf16: WT[n][k] = bf16(W[k][n]).  K,N mult of 32.
// ---------------------------------------------------------------------------
__global__ __launch_bounds__(256) void wtrans(
    const float* __restrict__ W, short* __restrict__ WT, int K, int N)
{
    __shared__ float t[32][33];
    const int n0 = blockIdx.x * 32, k0 = blockIdx.y * 32;
    const int lx = threadIdx.x & 31, ly = threadIdx.x >> 5;  // 32 x 8
#pragma unroll
    for (int r = 0; r < 4; ++r)
        t[ly + r * 8][lx] = W[(size_t)(k0 + ly + r * 8) * N + n0 + lx];
    __syncthreads();
#pragma unroll
    for (int r = 0; r < 4; ++r)
        WT[(size_t)(n0 + ly + r * 8) * K + k0 + lx] = f2bs(t[lx][ly + r * 8]);
}

// ---------------------------------------------------------------------------
// Projection GEMM: C[8192, N] = A(fp32)[8192,768] @ WT(bf16)[N,768]^T + bias
// mode 0: Q -> [b,h,s,d] scaled by log2e;  mode 1: K -> [b,g,s,d];
// mode 2: V -> [b,g,d,s] (transposed)
// BM=BN=128, BK=32; 256 thr = 4 waves (2x2), each wave 64x64.
// ---------------------------------------------------------------------------
__global__ __launch_bounds__(256) void proj_kernel(
    const float* __restrict__ A, const short* __restrict__ WT,
    const float* __restrict__ bias, short* __restrict__ out,
    int N, int mode)
{
    const int LS = 40;
    __shared__ short lA[128 * 40];
    __shared__ short lB[128 * 40];

    const int tid  = threadIdx.x;
    const int lane = tid & 63;
    const int wid  = tid >> 6;
    const int l16  = lane & 15;
    const int quad = lane >> 4;
    const int wm   = wid & 1;
    const int wn   = wid >> 1;
    const int bm   = blockIdx.x;
    const int bn   = blockIdx.y;

    v4f acc[4][4];
#pragma unroll
    for (int i = 0; i < 4; ++i)
#pragma unroll
        for (int j = 0; j < 4; ++j) acc[i][j] = (v4f){0.f, 0.f, 0.f, 0.f};

    for (int kt = 0; kt < 24; ++kt) {
        const int k0 = kt * 32;
        // A tile: fp32 -> bf16
#pragma unroll
        for (int r = 0; r < 4; ++r) {
            int f4  = tid + 256 * r;
            int row = f4 >> 3;
            int c4  = (f4 & 7) << 2;
            const float4 a = *reinterpret_cast<const float4*>(
                A + (size_t)(bm * 128 + row) * DMODEL + k0 + c4);
            s4pack p{f2bs(a.x), f2bs(a.y), f2bs(a.z), f2bs(a.w)};
            *reinterpret_cast<s4pack*>(&lA[row * LS + c4]) = p;
        }
        // B tile: straight bf16 b128 copy from pre-transposed weights
#pragma unroll
        for (int r = 0; r < 2; ++r) {
            int f8  = tid + 256 * r;
            int row = f8 >> 2;
            int c8  = (f8 & 3) << 3;
            *reinterpret_cast<v8s*>(&lB[row * LS + c8]) =
                *reinterpret_cast<const v8s*>(WT + (size_t)(bn * 128 + row) * DMODEL + k0 + c8);
        }
        __syncthreads();

        v8s af[4], bf[4];
#pragma unroll
        for (int i = 0; i < 4; ++i)
            af[i] = *reinterpret_cast<const v8s*>(&lA[(wm * 64 + i * 16 + l16) * LS + quad * 8]);
#pragma unroll
        for (int j = 0; j < 4; ++j)
            bf[j] = *reinterpret_cast<const v8s*>(&lB[(wn * 64 + j * 16 + l16) * LS + quad * 8]);
#pragma unroll
        for (int i = 0; i < 4; ++i)
#pragma unroll
            for (int j = 0; j < 4; ++j)
                acc[i][j] = __builtin_amdgcn_mfma_f32_16x16x32_bf16(af[i], bf[j], acc[i][j], 0, 0, 0);
        __syncthreads();
    }

    const float scale = (mode == 0) ? LOG2E : 1.0f;
#pragma unroll
    for (int i = 0; i < 4; ++i) {
#pragma unroll
        for (int j = 0; j < 4; ++j) {
            const int C = bn * 128 + wn * 64 + j * 16 + l16;
            const float bv = bias[C];
#pragma unroll
            for (int reg = 0; reg < 4; ++reg) {
                const int R = bm * 128 + wm * 64 + i * 16 + quad * 4 + reg;
                const float val = (acc[i][j][reg] + bv) * scale;
                const int b = R >> 11;
                const int s = R & 2047;
                const int sub = C >> 6;
                const int d = C & 63;
                size_t idx;
                if (mode == 0)      idx = ((size_t)(b * HEADS + sub) * SEQ + s) * DK + d;
                else if (mode == 1) idx = ((size_t)(b * GROUPS + sub) * SEQ + s) * DK + d;
                else                idx = ((size_t)(b * GROUPS + sub) * DK + d) * SEQ + s;
                out[idx] = f2bs(val);
            }
        }
    }
}

// ---------------------------------------------------------------------------
// Flash attention, no-max softmax (scores unscaled; Qp pre-scaled by log2e).
// grid (16 qtiles, 12 heads, 4 batch), 256 thr = 4 waves, 32 q-rows/wave.
// Row sums accumulated via ones-column in V (5th n-tile).
// ---------------------------------------------------------------------------
__global__ __launch_bounds__(256) void attn_kernel(
    const short* __restrict__ Qp, const short* __restrict__ Kp,
    const short* __restrict__ Vt, short* __restrict__ Oat)
{
    const int LS = 72;
    __shared__ short lK[64 * 72];       // [k_row][d]
    __shared__ short lV[80 * 72];       // [d][k_row], rows 64..79: ones/zeros
    __shared__ short lP[4][32 * 72];    // per-wave P [q_row][k_row]

    const int qt = blockIdx.x, h = blockIdx.y, b = blockIdx.z;
    const int g = h & 1;
    const int tid  = threadIdx.x;
    const int lane = tid & 63;
    const int wid  = tid >> 6;
    const int l16  = lane & 15;
    const int quad = lane >> 4;

    // init ones-column rows of lV (row 64 = 1.0, rows 65..79 = 0)
    {
        const int idx = tid * 4;
        const int row = 64 + (idx >> 6);
        const int col = idx & 63;
        const short val = (row == 64) ? (short)0x3F80 : (short)0;
        s4pack p{val, val, val, val};
        *reinterpret_cast<s4pack*>(&lV[row * LS + col]) = p;
    }

    // Q fragments: 2 m-tiles of 16 rows, resident all kernel
    v8s qf[2][2];
#pragma unroll
    for (int mi = 0; mi < 2; ++mi) {
        const size_t qbase =
            ((size_t)(b * HEADS + h) * SEQ + qt * 128 + wid * 32 + mi * 16 + l16) * DK;
        qf[mi][0] = *reinterpret_cast<const v8s*>(Qp + qbase + quad * 8);
        qf[mi][1] = *reinterpret_cast<const v8s*>(Qp + qbase + quad * 8 + 32);
    }

    const size_t kbase = (size_t)(b * GROUPS + g) * SEQ * DK;
    const size_t vbase = (size_t)(b * GROUPS + g) * DK * SEQ;

    v4f oacc[2][5];
#pragma unroll
    for (int mi = 0; mi < 2; ++mi)
#pragma unroll
        for (int n = 0; n < 5; ++n) oacc[mi][n] = (v4f){0.f, 0.f, 0.f, 0.f};

    for (int kt = 0; kt < 32; ++kt) {
        // stage K [64][64] and V^T [64][64]
#pragma unroll
        for (int r = 0; r < 2; ++r) {
            int i8  = tid + 256 * r;
            int row = i8 >> 3;
            int c8  = (i8 & 7) << 3;
            *reinterpret_cast<v8s*>(&lK[row * LS + c8]) =
                *reinterpret_cast<const v8s*>(Kp + kbase + (size_t)(kt * 64 + row) * DK + c8);
            *reinterpret_cast<v8s*>(&lV[row * LS + c8]) =
                *reinterpret_cast<const v8s*>(Vt + vbase + (size_t)row * SEQ + kt * 64 + c8);
        }
        __syncthreads();

        // S = Q K^T ; P = exp2(S) -> bf16 -> wave-private lP
#pragma unroll
        for (int j = 0; j < 4; ++j) {
            const v8s kf0 = *reinterpret_cast<const v8s*>(&lK[(j * 16 + l16) * LS + quad * 8]);
            const v8s kf1 = *reinterpret_cast<const v8s*>(&lK[(j * 16 + l16) * LS + quad * 8 + 32]);
#pragma unroll
            for (int mi = 0; mi < 2; ++mi) {
                v4f z = (v4f){0.f, 0.f, 0.f, 0.f};
                z = __builtin_amdgcn_mfma_f32_16x16x32_bf16(qf[mi][0], kf0, z, 0, 0, 0);
                z = __builtin_amdgcn_mfma_f32_16x16x32_bf16(qf[mi][1], kf1, z, 0, 0, 0);
#pragma unroll
                for (int reg = 0; reg < 4; ++reg)
                    lP[wid][(mi * 16 + quad * 4 + reg) * LS + j * 16 + l16] =
                        f2bs(fast_exp2(z[reg]));
            }
        }
        // no barrier: lP is wave-private (compiler inserts lgkmcnt waits)

        // O += P V  (n=4 accumulates row sums via ones-column)
#pragma unroll
        for (int kk = 0; kk < 2; ++kk) {
            v8s pf[2];
#pragma unroll
            for (int mi = 0; mi < 2; ++mi)
                pf[mi] = *reinterpret_cast<const v8s*>(
                    &lP[wid][(mi * 16 + l16) * LS + quad * 8 + kk * 32]);
#pragma unroll
            for (int n = 0; n < 5; ++n) {
                const v8s vf = *reinterpret_cast<const v8s*>(
                    &lV[(n * 16 + l16) * LS + quad * 8 + kk * 32]);
#pragma unroll
                for (int mi = 0; mi < 2; ++mi)
                    oacc[mi][n] = __builtin_amdgcn_mfma_f32_16x16x32_bf16(pf[mi], vf, oacc[mi][n], 0, 0, 0);
            }
        }
        __syncthreads();
    }

    // epilogue: divide by row sum (col 0 of n-tile 4, held by l16==0 lanes)
#pragma unroll
    for (int mi = 0; mi < 2; ++mi) {
        float rdiv[4];
#pragma unroll
        for (int reg = 0; reg < 4; ++reg) {
            const float s = __shfl(oacc[mi][4][reg], lane & 48, 64);
            rdiv[reg] = __builtin_amdgcn_rcpf(s);
        }
#pragma unroll
        for (int n = 0; n < 4; ++n)
#pragma unroll
            for (int reg = 0; reg < 4; ++reg) {
                const int qrow = qt * 128 + wid * 32 + mi * 16 + quad * 4 + reg;
                Oat[(size_t)(b * SEQ + qrow) * DMODEL + h * 64 + n * 16 + l16] =
                    f2bs(oacc[mi][n][reg] * rdiv[reg]);
            }
    }
}

// ---------------------------------------------------------------------------
// Output GEMM: out[8192,768] = Oat(bf16) @ WoT(bf16)[768,768]^T + bo, fp32
// ---------------------------------------------------------------------------
__global__ __launch_bounds__(256) void out_gemm(
    const short* __restrict__ A, const short* __restrict__ WT,
    const float* __restrict__ bias, float* __restrict__ out)
{
    const int LS = 40;
    __shared__ short lA[128 * 40];
    __shared__ short lB[128 * 40];

    const int tid  = threadIdx.x;
    const int lane = tid & 63;
    const int wid  = tid >> 6;
    const int l16  = lane & 15;
    const int quad = lane >> 4;
    const int wm   = wid & 1;
    const int wn   = wid >> 1;
    const int bm   = blockIdx.x;
    const int bn   = blockIdx.y;

    v4f acc[4][4];
#pragma unroll
    for (int i = 0; i < 4; ++i)
#pragma unroll
        for (int j = 0; j < 4; ++j) acc[i][j] = (v4f){0.f, 0.f, 0.f, 0.f};

    for (int kt = 0; kt < 24; ++kt) {
        const int k0 = kt * 32;
#pragma unroll
        for (int r = 0; r < 2; ++r) {
            int i8  = tid + 256 * r;
            int row = i8 >> 2;
            int c8  = (i8 & 3) << 3;
            *reinterpret_cast<v8s*>(&lA[row * LS + c8]) =
                *reinterpret_cast<const v8s*>(A + (size_t)(bm * 128 + row) * DMODEL + k0 + c8);
            *reinterpret_cast<v8s*>(&lB[row * LS + c8]) =
                *reinterpret_cast<const v8s*>(WT + (size_t)(bn * 128 + row) * DMODEL + k0 + c8);
        }
        __syncthreads();

        v8s af[4], bf[4];
#pragma unroll
        for (int i = 0; i < 4; ++i)
            af[i] = *reinterpret_cast<const v8s*>(&lA[(wm * 64 + i * 16 + l16) * LS + quad * 8]);
#pragma unroll
        for (int j = 0; j < 4; ++j)
            bf[j] = *reinterpret_cast<const v8s*>(&lB[(wn * 64 + j * 16 + l16) * LS + quad * 8]);
#pragma unroll
        for (int i = 0; i < 4; ++i)
#pragma unroll
            for (int j = 0; j < 4; ++j)
                acc[i][j] = __builtin_amdgcn_mfma_f32_16x16x32_bf16(af[i], bf[j], acc[i][j], 0, 0, 0);
        __syncthreads();
    }

#pragma unroll
    for (int i = 0; i < 4; ++i)
#pragma unroll
        for (int j = 0; j < 4; ++j) {
            const int C = bn * 128 + wn * 64 + j * 16 + l16;
            const float bv = bias[C];
#pragma unroll
            for (int reg = 0; reg < 4; ++reg) {
                const int R = bm * 128 + wm * 64 + i * 16 + quad * 4 + reg;
                out[(size_t)R * DMODEL + C] = acc[i][j][reg] + bv;
            }
        }
}

extern "C" void kernel_launch(void* const* d_in, const int* in_sizes, int n_in,
                              void* d_out, int out_size, void* d_ws, size_t ws_size,
                              hipStream_t stream) {
    const float* q  = (const float*)d_in[0];
    const float* k  = (const float*)d_in[1];
    const float* v  = (const float*)d_in[2];
    const float* Wq = (const float*)d_in[3];
    const float* bq = (const float*)d_in[4];
    const float* Wk = (const float*)d_in[5];
    const float* bk = (const float*)d_in[6];
    const float* Wv = (const float*)d_in[7];
    const float* bv = (const float*)d_in[8];
    const float* Wo = (const float*)d_in[9];
    const float* bo = (const float*)d_in[10];

    short* WqT = (short*)d_ws;                              // 589824
    short* WkT = WqT + 589824;                              // 98304
    short* WvT = WkT + 98304;                               // 98304
    short* WoT = WvT + 98304;                               // 589824
    short* Qp  = WoT + 589824;                              // [b,h,s,d]  6291456
    short* Kp  = Qp + (size_t)BS * HEADS * SEQ * DK;        // [b,g,s,d]  1048576
    short* Vt  = Kp + (size_t)BS * GROUPS * SEQ * DK;       // [b,g,d,s]  1048576
    short* Oat = Vt + (size_t)BS * GROUPS * SEQ * DK;       // [b,s,h*d]  6291456

    wtrans<<<dim3(24, 24), 256, 0, stream>>>(Wq, WqT, DMODEL, DMODEL);
    wtrans<<<dim3(4, 24), 256, 0, stream>>>(Wk, WkT, DMODEL, GROUPS * DK);
    wtrans<<<dim3(4, 24), 256, 0, stream>>>(Wv, WvT, DMODEL, GROUPS * DK);
    wtrans<<<dim3(24, 24), 256, 0, stream>>>(Wo, WoT, DMODEL, DMODEL);

    proj_kernel<<<dim3(64, 6), 256, 0, stream>>>(q, WqT, bq, Qp, DMODEL, 0);
    proj_kernel<<<dim3(64, 1), 256, 0, stream>>>(k, WkT, bk, Kp, GROUPS * DK, 1);
    proj_kernel<<<dim3(64, 1), 256, 0, stream>>>(v, WvT, bv, Vt, GROUPS * DK, 2);
    attn_kernel<<<dim3(16, HEADS, BS), 256, 0, stream>>>(Qp, Kp, Vt, Oat);
    out_gemm<<<dim3(64, 6), 256, 0, stream>>>(Oat, WoT, bo, (float*)d_out);
}

// Round 3
// 289.605 us; speedup vs baseline: 1.8547x; 1.2076x over previous
//
#include <hip/hip_runtime.h>
#include <hip/hip_bf16.h>

typedef short v8s __attribute__((ext_vector_type(8)));
typedef short v4s __attribute__((ext_vector_type(4)));
typedef float v4f __attribute__((ext_vector_type(4)));

#define BS 4
#define SEQ 2048
#define DMODEL 768
#define HEADS 12
#define GROUPS 2
#define DK 64
#define LOG2E 1.4426950408889634f

static __device__ __forceinline__ short f2bs(float f) {
    __hip_bfloat16 h = __float2bfloat16(f);
    return *reinterpret_cast<short*>(&h);
}

static __device__ __forceinline__ float fast_exp2(float x) {
#if __has_builtin(__builtin_amdgcn_exp2f)
    return __builtin_amdgcn_exp2f(x);
#else
    return __expf(x * 0.6931471805599453f);
#endif
}

// K=16 bf16 MFMA (CDNA2-era shape, present on gfx950 per ISA: v_mfma_f32_16x16x16_bf16)
static __device__ __forceinline__ v4f mfma16(v4s a, v4s b, v4f c) {
#if __has_builtin(__builtin_amdgcn_mfma_f32_16x16x16bf16_1k)
    return __builtin_amdgcn_mfma_f32_16x16x16bf16_1k(a, b, c, 0, 0, 0);
#else
    v4f d;
    asm("v_mfma_f32_16x16x16_bf16 %0, %1, %2, %3" : "=&v"(d) : "v"(a), "v"(b), "v"(c));
    return d;
#endif
}

struct alignas(8) s4pack { short a, b, c, d; };

// ---------------------------------------------------------------------------
// Fused weight transpose + fp32->bf16 for all 4 weights. K=768 always.
// z: 0=Wq(N=768) 1=Wo(768) 2=Wk(128) 3=Wv(128). grid (24,24,4).
// ---------------------------------------------------------------------------
__global__ __launch_bounds__(256) void wtrans_all(
    const float* __restrict__ Wq, const float* __restrict__ Wk,
    const float* __restrict__ Wv, const float* __restrict__ Wo,
    short* __restrict__ WqT, short* __restrict__ WkT,
    short* __restrict__ WvT, short* __restrict__ WoT)
{
    const int z = blockIdx.z;
    const float* W;
    short* WT;
    int N;
    if (z == 0)      { W = Wq; WT = WqT; N = 768; }
    else if (z == 1) { W = Wo; WT = WoT; N = 768; }
    else if (z == 2) { W = Wk; WT = WkT; N = 128; }
    else             { W = Wv; WT = WvT; N = 128; }
    const int n0 = blockIdx.x * 32, k0 = blockIdx.y * 32;
    if (n0 >= N) return;

    __shared__ float t[32][33];
    const int lx = threadIdx.x & 31, ly = threadIdx.x >> 5;  // 32 x 8
#pragma unroll
    for (int r = 0; r < 4; ++r)
        t[ly + r * 8][lx] = W[(size_t)(k0 + ly + r * 8) * N + n0 + lx];
    __syncthreads();
#pragma unroll
    for (int r = 0; r < 4; ++r)
        WT[(size_t)(n0 + ly + r * 8) * DMODEL + k0 + lx] = f2bs(t[lx][ly + r * 8]);
}

// ---------------------------------------------------------------------------
// Q projection: Qp[b,h,s,d] = bf16((q @ Wq + bq) * log2e)
// BM=BN=128, BK=32; 256 thr = 4 waves (2x2), each wave 64x64.
// ---------------------------------------------------------------------------
__global__ __launch_bounds__(256) void proj_q(
    const float* __restrict__ A, const short* __restrict__ WT,
    const float* __restrict__ bias, short* __restrict__ out)
{
    const int LS = 40;
    __shared__ short lA[128 * 40];
    __shared__ short lB[128 * 40];

    const int tid  = threadIdx.x;
    const int lane = tid & 63;
    const int wid  = tid >> 6;
    const int l16  = lane & 15;
    const int quad = lane >> 4;
    const int wm   = wid & 1;
    const int wn   = wid >> 1;
    const int bm   = blockIdx.x;
    const int bn   = blockIdx.y;

    v4f acc[4][4];
#pragma unroll
    for (int i = 0; i < 4; ++i)
#pragma unroll
        for (int j = 0; j < 4; ++j) acc[i][j] = (v4f){0.f, 0.f, 0.f, 0.f};

    for (int kt = 0; kt < 24; ++kt) {
        const int k0 = kt * 32;
#pragma unroll
        for (int r = 0; r < 4; ++r) {
            int f4  = tid + 256 * r;
            int row = f4 >> 3;
            int c4  = (f4 & 7) << 2;
            const float4 a = *reinterpret_cast<const float4*>(
                A + (size_t)(bm * 128 + row) * DMODEL + k0 + c4);
            s4pack p{f2bs(a.x), f2bs(a.y), f2bs(a.z), f2bs(a.w)};
            *reinterpret_cast<s4pack*>(&lA[row * LS + c4]) = p;
        }
#pragma unroll
        for (int r = 0; r < 2; ++r) {
            int f8  = tid + 256 * r;
            int row = f8 >> 2;
            int c8  = (f8 & 3) << 3;
            *reinterpret_cast<v8s*>(&lB[row * LS + c8]) =
                *reinterpret_cast<const v8s*>(WT + (size_t)(bn * 128 + row) * DMODEL + k0 + c8);
        }
        __syncthreads();

        v8s af[4], bf[4];
#pragma unroll
        for (int i = 0; i < 4; ++i)
            af[i] = *reinterpret_cast<const v8s*>(&lA[(wm * 64 + i * 16 + l16) * LS + quad * 8]);
#pragma unroll
        for (int j = 0; j < 4; ++j)
            bf[j] = *reinterpret_cast<const v8s*>(&lB[(wn * 64 + j * 16 + l16) * LS + quad * 8]);
#pragma unroll
        for (int i = 0; i < 4; ++i)
#pragma unroll
            for (int j = 0; j < 4; ++j)
                acc[i][j] = __builtin_amdgcn_mfma_f32_16x16x32_bf16(af[i], bf[j], acc[i][j], 0, 0, 0);
        __syncthreads();
    }

#pragma unroll
    for (int i = 0; i < 4; ++i) {
#pragma unroll
        for (int j = 0; j < 4; ++j) {
            const int C = bn * 128 + wn * 64 + j * 16 + l16;
            const float bv = bias[C];
#pragma unroll
            for (int reg = 0; reg < 4; ++reg) {
                const int R = bm * 128 + wm * 64 + i * 16 + quad * 4 + reg;
                const float val = (acc[i][j][reg] + bv) * LOG2E;
                const int b = R >> 11;
                const int s = R & 2047;
                const int h = C >> 6;
                const int d = C & 63;
                out[((size_t)(b * HEADS + h) * SEQ + s) * DK + d] = f2bs(val);
            }
        }
    }
}

// ---------------------------------------------------------------------------
// Fused K/V projection. blockIdx.y: 0=K -> [b,g,s,d], 1=V -> [b,g,d,s].
// BM=64, BN=128(=N), BK=32; 4 waves 2x2, wave tile 32x64. grid (128, 2).
// ---------------------------------------------------------------------------
__global__ __launch_bounds__(256) void proj_kv(
    const float* __restrict__ Ak, const float* __restrict__ Av,
    const short* __restrict__ WkT, const short* __restrict__ WvT,
    const float* __restrict__ bk, const float* __restrict__ bv,
    short* __restrict__ Kp, short* __restrict__ Vt)
{
    const int LS = 40;
    __shared__ short lA[64 * 40];
    __shared__ short lB[128 * 40];

    const int isV = blockIdx.y;
    const float* A  = isV ? Av : Ak;
    const short* WT = isV ? WvT : WkT;
    const float* bias = isV ? bv : bk;
    short* out = isV ? Vt : Kp;

    const int tid  = threadIdx.x;
    const int lane = tid & 63;
    const int wid  = tid >> 6;
    const int l16  = lane & 15;
    const int quad = lane >> 4;
    const int wm   = wid & 1;
    const int wn   = wid >> 1;
    const int bm   = blockIdx.x;

    v4f acc[2][4];
#pragma unroll
    for (int i = 0; i < 2; ++i)
#pragma unroll
        for (int j = 0; j < 4; ++j) acc[i][j] = (v4f){0.f, 0.f, 0.f, 0.f};

    for (int kt = 0; kt < 24; ++kt) {
        const int k0 = kt * 32;
#pragma unroll
        for (int r = 0; r < 2; ++r) {
            int f4  = tid + 256 * r;
            int row = f4 >> 3;
            int c4  = (f4 & 7) << 2;
            const float4 a = *reinterpret_cast<const float4*>(
                A + (size_t)(bm * 64 + row) * DMODEL + k0 + c4);
            s4pack p{f2bs(a.x), f2bs(a.y), f2bs(a.z), f2bs(a.w)};
            *reinterpret_cast<s4pack*>(&lA[row * LS + c4]) = p;
        }
#pragma unroll
        for (int r = 0; r < 2; ++r) {
            int f8  = tid + 256 * r;
            int row = f8 >> 2;
            int c8  = (f8 & 3) << 3;
            *reinterpret_cast<v8s*>(&lB[row * LS + c8]) =
                *reinterpret_cast<const v8s*>(WT + (size_t)row * DMODEL + k0 + c8);
        }
        __syncthreads();

        v8s af[2], bf[4];
#pragma unroll
        for (int i = 0; i < 2; ++i)
            af[i] = *reinterpret_cast<const v8s*>(&lA[(wm * 32 + i * 16 + l16) * LS + quad * 8]);
#pragma unroll
        for (int j = 0; j < 4; ++j)
            bf[j] = *reinterpret_cast<const v8s*>(&lB[(wn * 64 + j * 16 + l16) * LS + quad * 8]);
#pragma unroll
        for (int i = 0; i < 2; ++i)
#pragma unroll
            for (int j = 0; j < 4; ++j)
                acc[i][j] = __builtin_amdgcn_mfma_f32_16x16x32_bf16(af[i], bf[j], acc[i][j], 0, 0, 0);
        __syncthreads();
    }

#pragma unroll
    for (int i = 0; i < 2; ++i) {
#pragma unroll
        for (int j = 0; j < 4; ++j) {
            const int C = wn * 64 + j * 16 + l16;
            const float bvv = bias[C];
#pragma unroll
            for (int reg = 0; reg < 4; ++reg) {
                const int R = bm * 64 + wm * 32 + i * 16 + quad * 4 + reg;
                const float val = acc[i][j][reg] + bvv;
                const int b = R >> 11;
                const int s = R & 2047;
                const int g = C >> 6;
                const int d = C & 63;
                size_t idx;
                if (isV) idx = ((size_t)(b * GROUPS + g) * DK + d) * SEQ + s;
                else     idx = ((size_t)(b * GROUPS + g) * SEQ + s) * DK + d;
                out[idx] = f2bs(val);
            }
        }
    }
}

// ---------------------------------------------------------------------------
// Flash attention, no-max softmax. S^T trick: compute S^T = K·Q^T so the P
// C-layout (q=lane&15, k=quad*4+reg) IS the A-operand layout of the K=16
// MFMA — P never touches LDS. Row sums via constant-ones B-frag.
// grid (16 qtiles, 12 heads, 4 batch), 256 thr = 4 waves, 32 q-rows/wave.
// ---------------------------------------------------------------------------
__global__ __launch_bounds__(256) void attn_kernel(
    const short* __restrict__ Qp, const short* __restrict__ Kp,
    const short* __restrict__ Vt, short* __restrict__ Oat)
{
    const int LS = 72;
    __shared__ short lK[64 * 72];   // [k_row][d]
    __shared__ short lV[64 * 72];   // [d][k_row]

    const int qt = blockIdx.x, h = blockIdx.y, b = blockIdx.z;
    const int g = h & 1;
    const int tid  = threadIdx.x;
    const int lane = tid & 63;
    const int wid  = tid >> 6;
    const int l16  = lane & 15;
    const int quad = lane >> 4;

    // Q fragments (B-operand for S^T): Q[q=l16][d=quad*8+j]
    v8s qf[2][2];
#pragma unroll
    for (int mi = 0; mi < 2; ++mi) {
        const size_t qbase =
            ((size_t)(b * HEADS + h) * SEQ + qt * 128 + wid * 32 + mi * 16 + l16) * DK;
        qf[mi][0] = *reinterpret_cast<const v8s*>(Qp + qbase + quad * 8);
        qf[mi][1] = *reinterpret_cast<const v8s*>(Qp + qbase + quad * 8 + 32);
    }

    const size_t kbase = (size_t)(b * GROUPS + g) * SEQ * DK;
    const size_t vbase = (size_t)(b * GROUPS + g) * DK * SEQ;

    const v4s ones = {(short)0x3F80, (short)0x3F80, (short)0x3F80, (short)0x3F80};

    v4f oacc[2][5];
#pragma unroll
    for (int mi = 0; mi < 2; ++mi)
#pragma unroll
        for (int n = 0; n < 5; ++n) oacc[mi][n] = (v4f){0.f, 0.f, 0.f, 0.f};

    for (int kt = 0; kt < 32; ++kt) {
        // stage K [64][64] and V^T [64][64]
#pragma unroll
        for (int r = 0; r < 2; ++r) {
            int i8  = tid + 256 * r;
            int row = i8 >> 3;
            int c8  = (i8 & 7) << 3;
            *reinterpret_cast<v8s*>(&lK[row * LS + c8]) =
                *reinterpret_cast<const v8s*>(Kp + kbase + (size_t)(kt * 64 + row) * DK + c8);
            *reinterpret_cast<v8s*>(&lV[row * LS + c8]) =
                *reinterpret_cast<const v8s*>(Vt + vbase + (size_t)row * SEQ + kt * 64 + c8);
        }
        __syncthreads();

        // S^T blocks (j-th 16 k-rows): D[k][q]; P = exp2 packed -> A-frags
        v4s pp[2][4];   // [mi][j]
#pragma unroll
        for (int j = 0; j < 4; ++j) {
            const v8s kf0 = *reinterpret_cast<const v8s*>(&lK[(j * 16 + l16) * LS + quad * 8]);
            const v8s kf1 = *reinterpret_cast<const v8s*>(&lK[(j * 16 + l16) * LS + quad * 8 + 32]);
#pragma unroll
            for (int mi = 0; mi < 2; ++mi) {
                v4f z = (v4f){0.f, 0.f, 0.f, 0.f};
                z = __builtin_amdgcn_mfma_f32_16x16x32_bf16(kf0, qf[mi][0], z, 0, 0, 0);
                z = __builtin_amdgcn_mfma_f32_16x16x32_bf16(kf1, qf[mi][1], z, 0, 0, 0);
                v4s p;
#pragma unroll
                for (int reg = 0; reg < 4; ++reg) p[reg] = f2bs(fast_exp2(z[reg]));
                pp[mi][j] = p;
            }
        }

        // O += P V via K=16 MFMAs; n=4 is the ones-column row sum
#pragma unroll
        for (int j = 0; j < 4; ++j) {
#pragma unroll
            for (int n = 0; n < 4; ++n) {
                const v4s vf = *reinterpret_cast<const v4s*>(
                    &lV[(n * 16 + l16) * LS + j * 16 + quad * 4]);
#pragma unroll
                for (int mi = 0; mi < 2; ++mi)
                    oacc[mi][n] = mfma16(pp[mi][j], vf, oacc[mi][n]);
            }
#pragma unroll
            for (int mi = 0; mi < 2; ++mi)
                oacc[mi][4] = mfma16(pp[mi][j], ones, oacc[mi][4]);
        }
        __syncthreads();
    }

    // epilogue: O /= rowsum (col 0 of n-tile 4 via shfl), write [b,s,h*64+d]
#pragma unroll
    for (int mi = 0; mi < 2; ++mi) {
        float rdiv[4];
#pragma unroll
        for (int reg = 0; reg < 4; ++reg) {
            const float s = __shfl(oacc[mi][4][reg], lane & 48, 64);
            rdiv[reg] = __builtin_amdgcn_rcpf(s);
        }
#pragma unroll
        for (int n = 0; n < 4; ++n)
#pragma unroll
            for (int reg = 0; reg < 4; ++reg) {
                const int qrow = qt * 128 + wid * 32 + mi * 16 + quad * 4 + reg;
                Oat[(size_t)(b * SEQ + qrow) * DMODEL + h * 64 + n * 16 + l16] =
                    f2bs(oacc[mi][n][reg] * rdiv[reg]);
            }
    }
}

// ---------------------------------------------------------------------------
// Output GEMM: out[8192,768] = Oat(bf16) @ WoT(bf16)[768,768]^T + bo, fp32
// ---------------------------------------------------------------------------
__global__ __launch_bounds__(256) void out_gemm(
    const short* __restrict__ A, const short* __restrict__ WT,
    const float* __restrict__ bias, float* __restrict__ out)
{
    const int LS = 40;
    __shared__ short lA[128 * 40];
    __shared__ short lB[128 * 40];

    const int tid  = threadIdx.x;
    const int lane = tid & 63;
    const int wid  = tid >> 6;
    const int l16  = lane & 15;
    const int quad = lane >> 4;
    const int wm   = wid & 1;
    const int wn   = wid >> 1;
    const int bm   = blockIdx.x;
    const int bn   = blockIdx.y;

    v4f acc[4][4];
#pragma unroll
    for (int i = 0; i < 4; ++i)
#pragma unroll
        for (int j = 0; j < 4; ++j) acc[i][j] = (v4f){0.f, 0.f, 0.f, 0.f};

    for (int kt = 0; kt < 24; ++kt) {
        const int k0 = kt * 32;
#pragma unroll
        for (int r = 0; r < 2; ++r) {
            int i8  = tid + 256 * r;
            int row = i8 >> 2;
            int c8  = (i8 & 3) << 3;
            *reinterpret_cast<v8s*>(&lA[row * LS + c8]) =
                *reinterpret_cast<const v8s*>(A + (size_t)(bm * 128 + row) * DMODEL + k0 + c8);
            *reinterpret_cast<v8s*>(&lB[row * LS + c8]) =
                *reinterpret_cast<const v8s*>(WT + (size_t)(bn * 128 + row) * DMODEL + k0 + c8);
        }
        __syncthreads();

        v8s af[4], bf[4];
#pragma unroll
        for (int i = 0; i < 4; ++i)
            af[i] = *reinterpret_cast<const v8s*>(&lA[(wm * 64 + i * 16 + l16) * LS + quad * 8]);
#pragma unroll
        for (int j = 0; j < 4; ++j)
            bf[j] = *reinterpret_cast<const v8s*>(&lB[(wn * 64 + j * 16 + l16) * LS + quad * 8]);
#pragma unroll
        for (int i = 0; i < 4; ++i)
#pragma unroll
            for (int j = 0; j < 4; ++j)
                acc[i][j] = __builtin_amdgcn_mfma_f32_16x16x32_bf16(af[i], bf[j], acc[i][j], 0, 0, 0);
        __syncthreads();
    }

#pragma unroll
    for (int i = 0; i < 4; ++i)
#pragma unroll
        for (int j = 0; j < 4; ++j) {
            const int C = bn * 128 + wn * 64 + j * 16 + l16;
            const float bv = bias[C];
#pragma unroll
            for (int reg = 0; reg < 4; ++reg) {
                const int R = bm * 128 + wm * 64 + i * 16 + quad * 4 + reg;
                out[(size_t)R * DMODEL + C] = acc[i][j][reg] + bv;
            }
        }
}

extern "C" void kernel_launch(void* const* d_in, const int* in_sizes, int n_in,
                              void* d_out, int out_size, void* d_ws, size_t ws_size,
                              hipStream_t stream) {
    const float* q  = (const float*)d_in[0];
    const float* k  = (const float*)d_in[1];
    const float* v  = (const float*)d_in[2];
    const float* Wq = (const float*)d_in[3];
    const float* bq = (const float*)d_in[4];
    const float* Wk = (const float*)d_in[5];
    const float* bk = (const float*)d_in[6];
    const float* Wv = (const float*)d_in[7];
    const float* bv = (const float*)d_in[8];
    const float* Wo = (const float*)d_in[9];
    const float* bo = (const float*)d_in[10];

    short* WqT = (short*)d_ws;                              // 589824
    short* WkT = WqT + 589824;                              // 98304
    short* WvT = WkT + 98304;                               // 98304
    short* WoT = WvT + 98304;                               // 589824
    short* Qp  = WoT + 589824;                              // [b,h,s,d]  6291456
    short* Kp  = Qp + (size_t)BS * HEADS * SEQ * DK;        // [b,g,s,d]  1048576
    short* Vt  = Kp + (size_t)BS * GROUPS * SEQ * DK;       // [b,g,d,s]  1048576
    short* Oat = Vt + (size_t)BS * GROUPS * SEQ * DK;       // [b,s,h*d]  6291456

    wtrans_all<<<dim3(24, 24, 4), 256, 0, stream>>>(Wq, Wk, Wv, Wo, WqT, WkT, WvT, WoT);
    proj_q<<<dim3(64, 6), 256, 0, stream>>>(q, WqT, bq, Qp);
    proj_kv<<<dim3(128, 2), 256, 0, stream>>>(k, v, WkT, WvT, bk, bv, Kp, Vt);
    attn_kernel<<<dim3(16, HEADS, BS), 256, 0, stream>>>(Qp, Kp, Vt, Oat);
    out_gemm<<<dim3(64, 6), 256, 0, stream>>>(Oat, WoT, bo, (float*)d_out);
}

// Round 5
// 259.203 us; speedup vs baseline: 2.0722x; 1.1173x over previous
//
#include <hip/hip_runtime.h>
#include <hip/hip_bf16.h>

typedef short v8s __attribute__((ext_vector_type(8)));
typedef short v4s __attribute__((ext_vector_type(4)));
typedef float v4f __attribute__((ext_vector_type(4)));

#define BS 4
#define SEQ 2048
#define DMODEL 768
#define HEADS 12
#define GROUPS 2
#define DK 64
#define LOG2E 1.4426950408889634f

static __device__ __forceinline__ short f2bs(float f) {
    __hip_bfloat16 h = __float2bfloat16(f);
    return *reinterpret_cast<short*>(&h);
}

static __device__ __forceinline__ float fast_exp2(float x) {
#if __has_builtin(__builtin_amdgcn_exp2f)
    return __builtin_amdgcn_exp2f(x);
#else
    return __expf(x * 0.6931471805599453f);
#endif
}

struct alignas(8) s4pack { short a, b, c, d; };

// ---------------------------------------------------------------------------
// q fp32 -> bf16 (one pass; avoids 6x redundant fp32 A-reads in proj).
// grid 1536 x 256; 4096 elems/block.
// ---------------------------------------------------------------------------
__global__ __launch_bounds__(256) void convert_q(
    const float* __restrict__ q, short* __restrict__ qbf)
{
    const size_t base = (size_t)blockIdx.x * 4096;
#pragma unroll
    for (int r = 0; r < 4; ++r) {
        const size_t i = base + r * 1024 + threadIdx.x * 4;
        const float4 a = *reinterpret_cast<const float4*>(q + i);
        s4pack p{f2bs(a.x), f2bs(a.y), f2bs(a.z), f2bs(a.w)};
        *reinterpret_cast<s4pack*>(qbf + i) = p;
    }
}

// ---------------------------------------------------------------------------
// Fused weight transpose + fp32->bf16. z: 0=Wq 1=Wo 2=Wk 3=Wv. grid (24,24,4).
// ---------------------------------------------------------------------------
__global__ __launch_bounds__(256) void wtrans_all(
    const float* __restrict__ Wq, const float* __restrict__ Wk,
    const float* __restrict__ Wv, const float* __restrict__ Wo,
    short* __restrict__ WqT, short* __restrict__ WkT,
    short* __restrict__ WvT, short* __restrict__ WoT)
{
    const int z = blockIdx.z;
    const float* W;
    short* WT;
    int N;
    if (z == 0)      { W = Wq; WT = WqT; N = 768; }
    else if (z == 1) { W = Wo; WT = WoT; N = 768; }
    else if (z == 2) { W = Wk; WT = WkT; N = 128; }
    else             { W = Wv; WT = WvT; N = 128; }
    const int n0 = blockIdx.x * 32, k0 = blockIdx.y * 32;
    if (n0 >= N) return;

    __shared__ float t[32][33];
    const int lx = threadIdx.x & 31, ly = threadIdx.x >> 5;
#pragma unroll
    for (int r = 0; r < 4; ++r)
        t[ly + r * 8][lx] = W[(size_t)(k0 + ly + r * 8) * N + n0 + lx];
    __syncthreads();
#pragma unroll
    for (int r = 0; r < 4; ++r)
        WT[(size_t)(n0 + ly + r * 8) * DMODEL + k0 + lx] = f2bs(t[lx][ly + r * 8]);
}

// ---------------------------------------------------------------------------
// Unified projection. grid (128, 8): y<6 -> Q slice bn=y (bf16 A, *log2e);
// y==6 -> K; y==7 -> V(transposed). BM=64, BN=128, BK=32.
// 4 waves 2x2, wave tile 32x64. 1024 blocks = 4/CU.
// NOTE: WT pointer must include the y*128 slice offset for Q (round-4 bug).
// ---------------------------------------------------------------------------
__global__ __launch_bounds__(256) void proj_all(
    const short* __restrict__ qbf, const float* __restrict__ kin,
    const float* __restrict__ vin,
    const short* __restrict__ WqT, const short* __restrict__ WkT,
    const short* __restrict__ WvT,
    const float* __restrict__ bq, const float* __restrict__ bk,
    const float* __restrict__ bv,
    short* __restrict__ Qp, short* __restrict__ Kp, short* __restrict__ Vt)
{
    const int LS = 40;
    __shared__ short lA[64 * 40];
    __shared__ short lB[128 * 40];

    const int y = blockIdx.y;
    const short* WT = (y < 6) ? WqT + (size_t)y * 128 * DMODEL
                              : (y == 6) ? WkT : WvT;
    const float* bias = (y < 6) ? bq + y * 128 : (y == 6) ? bk : bv;

    const int tid  = threadIdx.x;
    const int lane = tid & 63;
    const int wid  = tid >> 6;
    const int l16  = lane & 15;
    const int quad = lane >> 4;
    const int wm   = wid & 1;
    const int wn   = wid >> 1;
    const int bm   = blockIdx.x;

    v4f acc[2][4];
#pragma unroll
    for (int i = 0; i < 2; ++i)
#pragma unroll
        for (int j = 0; j < 4; ++j) acc[i][j] = (v4f){0.f, 0.f, 0.f, 0.f};

    for (int kt = 0; kt < 24; ++kt) {
        const int k0 = kt * 32;
        if (y < 6) {
            // bf16 A: one v8s per thread
            const int row = tid >> 2, c8 = (tid & 3) << 3;
            *reinterpret_cast<v8s*>(&lA[row * LS + c8]) =
                *reinterpret_cast<const v8s*>(qbf + (size_t)(bm * 64 + row) * DMODEL + k0 + c8);
        } else {
            const float* A = (y == 6) ? kin : vin;
#pragma unroll
            for (int r = 0; r < 2; ++r) {
                int f4  = tid + 256 * r;
                int row = f4 >> 3;
                int c4  = (f4 & 7) << 2;
                const float4 a = *reinterpret_cast<const float4*>(
                    A + (size_t)(bm * 64 + row) * DMODEL + k0 + c4);
                s4pack p{f2bs(a.x), f2bs(a.y), f2bs(a.z), f2bs(a.w)};
                *reinterpret_cast<s4pack*>(&lA[row * LS + c4]) = p;
            }
        }
#pragma unroll
        for (int r = 0; r < 2; ++r) {
            int f8  = tid + 256 * r;
            int row = f8 >> 2;
            int c8  = (f8 & 3) << 3;
            *reinterpret_cast<v8s*>(&lB[row * LS + c8]) =
                *reinterpret_cast<const v8s*>(WT + (size_t)row * DMODEL + k0 + c8);
        }
        __syncthreads();

        v8s af[2], bf[4];
#pragma unroll
        for (int i = 0; i < 2; ++i)
            af[i] = *reinterpret_cast<const v8s*>(&lA[(wm * 32 + i * 16 + l16) * LS + quad * 8]);
#pragma unroll
        for (int j = 0; j < 4; ++j)
            bf[j] = *reinterpret_cast<const v8s*>(&lB[(wn * 64 + j * 16 + l16) * LS + quad * 8]);
#pragma unroll
        for (int i = 0; i < 2; ++i)
#pragma unroll
            for (int j = 0; j < 4; ++j)
                acc[i][j] = __builtin_amdgcn_mfma_f32_16x16x32_bf16(af[i], bf[j], acc[i][j], 0, 0, 0);
        __syncthreads();
    }

#pragma unroll
    for (int i = 0; i < 2; ++i) {
#pragma unroll
        for (int j = 0; j < 4; ++j) {
            const int Cl = wn * 64 + j * 16 + l16;   // 0..127 within this slice
            const float bvv = bias[Cl];
#pragma unroll
            for (int reg = 0; reg < 4; ++reg) {
                const int R = bm * 64 + wm * 32 + i * 16 + quad * 4 + reg;
                const int b = R >> 11;
                const int s = R & 2047;
                if (y < 6) {
                    const int C = y * 128 + Cl;
                    const int h = C >> 6, d = C & 63;
                    Qp[((size_t)(b * HEADS + h) * SEQ + s) * DK + d] =
                        f2bs((acc[i][j][reg] + bvv) * LOG2E);
                } else if (y == 6) {
                    const int g = Cl >> 6, d = Cl & 63;
                    Kp[((size_t)(b * GROUPS + g) * SEQ + s) * DK + d] =
                        f2bs(acc[i][j][reg] + bvv);
                } else {
                    const int g = Cl >> 6, d = Cl & 63;
                    Vt[((size_t)(b * GROUPS + g) * DK + d) * SEQ + s] =
                        f2bs(acc[i][j][reg] + bvv);
                }
            }
        }
    }
}

// ---------------------------------------------------------------------------
// Flash attention, no-max softmax, S^T trick + K=32 PV via k-permuted V tile.
// Permutation (verified: k=5 -> ck=9 -> (quad=1,i=1) -> 5; k=20 -> ck=12 ->
// (quad=1,i=4) -> 20): actual k a=[cj|u|q:2|r:2] stored at ck=[cj|q:2|u|r:2];
// then concat(pp[2cj],pp[2cj+1]) IS a valid K=32 A-frag.
// grid (16 qtiles, 12 heads, 4 batch), 256 thr = 4 waves, 32 q-rows/wave.
// ---------------------------------------------------------------------------
__global__ __launch_bounds__(256) void attn_kernel(
    const short* __restrict__ Qp, const short* __restrict__ Kp,
    const short* __restrict__ Vt, short* __restrict__ Oat)
{
    const int LS = 72;
    __shared__ short lK[64 * 72];   // [k_row][d], natural order
    __shared__ short lV[64 * 72];   // [d][ck], k-permuted columns

    const int qt = blockIdx.x, h = blockIdx.y, b = blockIdx.z;
    const int g = h & 1;
    const int tid  = threadIdx.x;
    const int lane = tid & 63;
    const int wid  = tid >> 6;
    const int l16  = lane & 15;
    const int quad = lane >> 4;

    v8s qf[2][2];
#pragma unroll
    for (int mi = 0; mi < 2; ++mi) {
        const size_t qbase =
            ((size_t)(b * HEADS + h) * SEQ + qt * 128 + wid * 32 + mi * 16 + l16) * DK;
        qf[mi][0] = *reinterpret_cast<const v8s*>(Qp + qbase + quad * 8);
        qf[mi][1] = *reinterpret_cast<const v8s*>(Qp + qbase + quad * 8 + 32);
    }

    const size_t kbase = (size_t)(b * GROUPS + g) * SEQ * DK;
    const size_t vbase = (size_t)(b * GROUPS + g) * DK * SEQ;

    const short one = (short)0x3F80;
    const v8s ones8 = {one, one, one, one, one, one, one, one};

    v4f oacc[2][5];
#pragma unroll
    for (int mi = 0; mi < 2; ++mi)
#pragma unroll
        for (int n = 0; n < 5; ++n) oacc[mi][n] = (v4f){0.f, 0.f, 0.f, 0.f};

    for (int kt = 0; kt < 32; ++kt) {
        // stage K [64][64] natural; V^T [64][64] with permuted columns
#pragma unroll
        for (int r = 0; r < 2; ++r) {
            int i8  = tid + 256 * r;
            int row = i8 >> 3;
            int c8  = (i8 & 7) << 3;
            *reinterpret_cast<v8s*>(&lK[row * LS + c8]) =
                *reinterpret_cast<const v8s*>(Kp + kbase + (size_t)(kt * 64 + row) * DK + c8);
            const v8s w = *reinterpret_cast<const v8s*>(
                Vt + vbase + (size_t)row * SEQ + kt * 64 + c8);
            const int a0 = c8, a1 = c8 + 4;
            const int ck0 = (a0 & 0x23) | ((a0 & 0x0C) << 1) | ((a0 & 0x10) >> 2);
            const int ck1 = (a1 & 0x23) | ((a1 & 0x0C) << 1) | ((a1 & 0x10) >> 2);
            s4pack lo{w[0], w[1], w[2], w[3]};
            s4pack hi{w[4], w[5], w[6], w[7]};
            *reinterpret_cast<s4pack*>(&lV[row * LS + ck0]) = lo;
            *reinterpret_cast<s4pack*>(&lV[row * LS + ck1]) = hi;
        }
        __syncthreads();

        // S^T = K Q^T per 16-k block j; P = exp2 packed to bf16 in regs
        v4s pp[2][4];   // [mi][j]
#pragma unroll
        for (int j = 0; j < 4; ++j) {
            const v8s kf0 = *reinterpret_cast<const v8s*>(&lK[(j * 16 + l16) * LS + quad * 8]);
            const v8s kf1 = *reinterpret_cast<const v8s*>(&lK[(j * 16 + l16) * LS + quad * 8 + 32]);
#pragma unroll
            for (int mi = 0; mi < 2; ++mi) {
                v4f z = (v4f){0.f, 0.f, 0.f, 0.f};
                z = __builtin_amdgcn_mfma_f32_16x16x32_bf16(kf0, qf[mi][0], z, 0, 0, 0);
                z = __builtin_amdgcn_mfma_f32_16x16x32_bf16(kf1, qf[mi][1], z, 0, 0, 0);
                v4s p;
#pragma unroll
                for (int reg = 0; reg < 4; ++reg) p[reg] = f2bs(fast_exp2(z[reg]));
                pp[mi][j] = p;
            }
        }

        // O += P V via K=32 MFMAs over permuted columns; ones = rowsum
#pragma unroll
        for (int cj = 0; cj < 2; ++cj) {
            v8s pf[2];
#pragma unroll
            for (int mi = 0; mi < 2; ++mi)
                pf[mi] = __builtin_shufflevector(pp[mi][2 * cj], pp[mi][2 * cj + 1],
                                                 0, 1, 2, 3, 4, 5, 6, 7);
#pragma unroll
            for (int n = 0; n < 4; ++n) {
                const v8s vf = *reinterpret_cast<const v8s*>(
                    &lV[(n * 16 + l16) * LS + cj * 32 + quad * 8]);
#pragma unroll
                for (int mi = 0; mi < 2; ++mi)
                    oacc[mi][n] = __builtin_amdgcn_mfma_f32_16x16x32_bf16(pf[mi], vf, oacc[mi][n], 0, 0, 0);
            }
#pragma unroll
            for (int mi = 0; mi < 2; ++mi)
                oacc[mi][4] = __builtin_amdgcn_mfma_f32_16x16x32_bf16(pf[mi], ones8, oacc[mi][4], 0, 0, 0);
        }
        __syncthreads();
    }

    // epilogue: every lane of the ones-tile holds its own rowsum
#pragma unroll
    for (int mi = 0; mi < 2; ++mi) {
        float rdiv[4];
#pragma unroll
        for (int reg = 0; reg < 4; ++reg)
            rdiv[reg] = __builtin_amdgcn_rcpf(oacc[mi][4][reg]);
#pragma unroll
        for (int n = 0; n < 4; ++n)
#pragma unroll
            for (int reg = 0; reg < 4; ++reg) {
                const int qrow = qt * 128 + wid * 32 + mi * 16 + quad * 4 + reg;
                Oat[(size_t)(b * SEQ + qrow) * DMODEL + h * 64 + n * 16 + l16] =
                    f2bs(oacc[mi][n][reg] * rdiv[reg]);
            }
    }
}

// ---------------------------------------------------------------------------
// Output GEMM: out[8192,768] = Oat(bf16) @ WoT^T + bo, fp32.
// BM=64, BN=128: grid (128,6) = 768 blocks = 3/CU.
// ---------------------------------------------------------------------------
__global__ __launch_bounds__(256) void out_gemm(
    const short* __restrict__ A, const short* __restrict__ WT,
    const float* __restrict__ bias, float* __restrict__ out)
{
    const int LS = 40;
    __shared__ short lA[64 * 40];
    __shared__ short lB[128 * 40];

    const int tid  = threadIdx.x;
    const int lane = tid & 63;
    const int wid  = tid >> 6;
    const int l16  = lane & 15;
    const int quad = lane >> 4;
    const int wm   = wid & 1;
    const int wn   = wid >> 1;
    const int bm   = blockIdx.x;
    const int bn   = blockIdx.y;

    v4f acc[2][4];
#pragma unroll
    for (int i = 0; i < 2; ++i)
#pragma unroll
        for (int j = 0; j < 4; ++j) acc[i][j] = (v4f){0.f, 0.f, 0.f, 0.f};

    for (int kt = 0; kt < 24; ++kt) {
        const int k0 = kt * 32;
        {
            const int row = tid >> 2, c8 = (tid & 3) << 3;
            *reinterpret_cast<v8s*>(&lA[row * LS + c8]) =
                *reinterpret_cast<const v8s*>(A + (size_t)(bm * 64 + row) * DMODEL + k0 + c8);
        }
#pragma unroll
        for (int r = 0; r < 2; ++r) {
            int f8  = tid + 256 * r;
            int row = f8 >> 2;
            int c8  = (f8 & 3) << 3;
            *reinterpret_cast<v8s*>(&lB[row * LS + c8]) =
                *reinterpret_cast<const v8s*>(WT + (size_t)(bn * 128 + row) * DMODEL + k0 + c8);
        }
        __syncthreads();

        v8s af[2], bf[4];
#pragma unroll
        for (int i = 0; i < 2; ++i)
            af[i] = *reinterpret_cast<const v8s*>(&lA[(wm * 32 + i * 16 + l16) * LS + quad * 8]);
#pragma unroll
        for (int j = 0; j < 4; ++j)
            bf[j] = *reinterpret_cast<const v8s*>(&lB[(wn * 64 + j * 16 + l16) * LS + quad * 8]);
#pragma unroll
        for (int i = 0; i < 2; ++i)
#pragma unroll
            for (int j = 0; j < 4; ++j)
                acc[i][j] = __builtin_amdgcn_mfma_f32_16x16x32_bf16(af[i], bf[j], acc[i][j], 0, 0, 0);
        __syncthreads();
    }

#pragma unroll
    for (int i = 0; i < 2; ++i)
#pragma unroll
        for (int j = 0; j < 4; ++j) {
            const int C = bn * 128 + wn * 64 + j * 16 + l16;
            const float bv = bias[C];
#pragma unroll
            for (int reg = 0; reg < 4; ++reg) {
                const int R = bm * 64 + wm * 32 + i * 16 + quad * 4 + reg;
                out[(size_t)R * DMODEL + C] = acc[i][j][reg] + bv;
            }
        }
}

extern "C" void kernel_launch(void* const* d_in, const int* in_sizes, int n_in,
                              void* d_out, int out_size, void* d_ws, size_t ws_size,
                              hipStream_t stream) {
    const float* q  = (const float*)d_in[0];
    const float* k  = (const float*)d_in[1];
    const float* v  = (const float*)d_in[2];
    const float* Wq = (const float*)d_in[3];
    const float* bq = (const float*)d_in[4];
    const float* Wk = (const float*)d_in[5];
    const float* bk = (const float*)d_in[6];
    const float* Wv = (const float*)d_in[7];
    const float* bv = (const float*)d_in[8];
    const float* Wo = (const float*)d_in[9];
    const float* bo = (const float*)d_in[10];

    short* WqT = (short*)d_ws;                              // 589824
    short* WkT = WqT + 589824;                              // 98304
    short* WvT = WkT + 98304;                               // 98304
    short* WoT = WvT + 98304;                               // 589824
    short* qbf = WoT + 589824;                              // 6291456
    short* Qp  = qbf + 6291456;                             // [b,h,s,d]  6291456
    short* Kp  = Qp + (size_t)BS * HEADS * SEQ * DK;        // [b,g,s,d]  1048576
    short* Vt  = Kp + (size_t)BS * GROUPS * SEQ * DK;       // [b,g,d,s]  1048576
    short* Oat = Vt + (size_t)BS * GROUPS * SEQ * DK;       // [b,s,h*d]  6291456

    convert_q<<<1536, 256, 0, stream>>>(q, qbf);
    wtrans_all<<<dim3(24, 24, 4), 256, 0, stream>>>(Wq, Wk, Wv, Wo, WqT, WkT, WvT, WoT);
    proj_all<<<dim3(128, 8), 256, 0, stream>>>(qbf, k, v, WqT, WkT, WvT,
                                               bq, bk, bv, Qp, Kp, Vt);
    attn_kernel<<<dim3(16, HEADS, BS), 256, 0, stream>>>(Qp, Kp, Vt, Oat);
    out_gemm<<<dim3(128, 6), 256, 0, stream>>>(Oat, WoT, bo, (float*)d_out);
}